// Round 6
// baseline (739.377 us; speedup 1.0000x reference)
//
#include <hip/hip_runtime.h>

#define BB    64
#define TT    256
#define EMBD  300
#define HIDD  512
#define OUTC  10
#define THETA 10.0
#define FUTN  12     // >= Kr-1 (Kr expected 11)
#define KSMAX 80     // >= Ks (expected 77), srm zero-padded
#define XSTR  260    // LDS x row stride (floats)
#define WSTR  34     // LDS w row stride (doubles), even -> 16B-aligned b128 rows
#define HSTR  257    // LDS h row stride (doubles)
#define CTILE 32

// ---------------- tiny: W2 f32 -> f64 ---------------------------------------
__global__ __launch_bounds__(256)
void w2cvt_kernel(const float* __restrict__ W2, double* __restrict__ w2d)
{
    const int k = blockIdx.x * 256 + threadIdx.x;
    if (k < OUTC * HIDD) w2d[k] = (double)W2[k];
}

// ------- gemm1: m1[b][c-cbase][t] = sum_e W1[c][e] * emb[feed[b][t]][e] -----
__global__ __launch_bounds__(256, 3)
void gemm1_kernel(const int* __restrict__ feed, const float* __restrict__ emb,
                  const float* __restrict__ W1, double* __restrict__ m1,
                  int cbase, int chn)
{
    __shared__ float  xs[16 * XSTR];   // [e][t] f32, 16.6 KB
    __shared__ double wl[16 * WSTR];   // [e][c] f64, 4.4 KB
    __shared__ int    idxb[TT];

    const int tid = threadIdx.x;
    const int c0l = blockIdx.x * CTILE;      // local channel base in chunk
    const int c0  = cbase + c0l;             // global channel base
    const int b   = blockIdx.y;

    idxb[tid] = feed[b * TT + tid];
    __syncthreads();

    const int cg = tid >> 6, tg = tid & 63;   // compute: c=8cg+j, t=4tg+i
    const int es = tid & 15, ts = tid >> 4;   // staging: e lane, t base

    int myidx[16];
#pragma unroll
    for (int k = 0; k < 16; ++k) myidx[k] = idxb[ts + 16 * k];

    double acc[4][8];
#pragma unroll
    for (int i = 0; i < 4; ++i)
#pragma unroll
        for (int j = 0; j < 8; ++j) acc[i][j] = 0.0;

    const int NCH = (EMBD + 15) / 16;  // 19
    for (int ch = 0; ch < NCH; ++ch) {
        const int e0 = ch * 16;
        const int ec = min(16, EMBD - e0);
        // stage x: xs[e][t] = emb[idx[t]][e0+e]
        if (es < ec) {
#pragma unroll
            for (int k = 0; k < 16; ++k) {
                const int t = ts + 16 * k;
                xs[es * XSTR + t] = emb[(size_t)myidx[k] * EMBD + e0 + es];
            }
        }
        // stage w: 32c x 16e, f64
        {
            int u = tid;
#pragma unroll
            for (int rep = 0; rep < 2; ++rep) {
                const int c = u >> 4, e = u & 15;
                if (e < ec)
                    wl[e * WSTR + c] = (double)W1[(size_t)(c0 + c) * EMBD + e0 + e];
                u += 256;
            }
        }
        __syncthreads();
        for (int e = 0; e < ec; ++e) {
            const float4  xv = *(const float4*)&xs[e * XSTR + 4 * tg];
            const double* wp = &wl[e * WSTR + 8 * cg];
            const double2 w01 = *(const double2*)(wp + 0);
            const double2 w23 = *(const double2*)(wp + 2);
            const double2 w45 = *(const double2*)(wp + 4);
            const double2 w67 = *(const double2*)(wp + 6);
            const double wv[8] = { w01.x, w01.y, w23.x, w23.y,
                                   w45.x, w45.y, w67.x, w67.y };
            const double xd[4] = { (double)xv.x, (double)xv.y,
                                   (double)xv.z, (double)xv.w };
#pragma unroll
            for (int i = 0; i < 4; ++i)
#pragma unroll
                for (int j = 0; j < 8; ++j)
                    acc[i][j] = fma(xd[i], wv[j], acc[i][j]);
        }
        __syncthreads();
    }

    // write m1 (coalesced: 64 lanes x 32B per c-row)
#pragma unroll
    for (int j = 0; j < 8; ++j) {
        double* dst = &m1[((size_t)b * chn + c0l + 8 * cg + j) * TT + 4 * tg];
        *(double2*)(dst + 0) = make_double2(acc[0][j], acc[1][j]);
        *(double2*)(dst + 2) = make_double2(acc[2][j], acc[3][j]);
    }
}

// ---------------- firscan: psp FIR + spike scan per (b, 16c) ----------------
__global__ __launch_bounds__(256, 4)
void firscan_kernel(const double* __restrict__ m1, const float* __restrict__ srm,
                    const float* __restrict__ refk, unsigned char* __restrict__ s1,
                    int Ks, int Kr, int cbase, int chn)
{
    __shared__ double        h[16 * HSTR];     // 32.9 KB
    __shared__ unsigned char sb[16 * 260];     // 4.2 KB
    __shared__ double        srm_sm[KSMAX];

    const int tid = threadIdx.x;
    const int c0l = blockIdx.x * 16;
    const int b   = blockIdx.y;

    if (tid < KSMAX) srm_sm[tid] = (tid < Ks) ? (double)srm[tid] : 0.0;

    for (int u = tid; u < 16 * TT; u += 256)
        h[(u >> 8) * HSTR + (u & 255)] =
            m1[((size_t)b * chn + c0l + (u >> 8)) * TT + (u & 255)];
    __syncthreads();

    // FIR: two passes of 8 outputs; j ascending 0..KSMAX-1 -> bit-identical
    const int cf = tid & 15, tb = tid >> 4;
    const double* hrow = &h[cf * HSTR];
    double pout[16];
#pragma unroll
    for (int k = 0; k < 16; ++k) pout[k] = 0.0;
#pragma unroll
    for (int pp = 0; pp < 2; ++pp) {
        const int t0 = tb * 16 + pp * 8;
        double win[8];
#pragma unroll
        for (int k = 0; k < 8; ++k) win[k] = hrow[t0 + k];
        for (int jb = 0; jb < KSMAX; jb += 8) {
#pragma unroll
            for (int jj = 0; jj < 8; ++jj) {
                const double sj = srm_sm[jb + jj];
#pragma unroll
                for (int i = 0; i < 8; ++i)
                    pout[pp * 8 + i] = fma(win[(8 + i - jj) & 7], sj, pout[pp * 8 + i]);
                const int idx = t0 - (jb + jj) - 1;
                win[(7 - jj) & 7] = (idx >= 0) ? hrow[idx] : 0.0;
            }
        }
    }
    __syncthreads();                   // all FIR reads done before overwrite
#pragma unroll
    for (int k = 0; k < 16; ++k)
        h[cf * HSTR + tb * 16 + k] = pout[k];
    __syncthreads();

    // spike scan: 16 lanes, one per channel
    if (tid < 16) {
        double fut[FUTN], rsh[FUTN];
#pragma unroll
        for (int i = 0; i < FUTN; ++i) {
            fut[i] = (i + 1 < Kr) ? (double)refk[i + 1] : 0.0;
            rsh[i] = 0.0;
        }
        const double*  hr = &h[tid * HSTR];
        unsigned char* sr = &sb[tid * 260];
        for (int t = 0; t < TT; ++t) {
            const double m  = hr[t] + rsh[0];
            const double sv = (m >= THETA) ? 1.0 : 0.0;
#pragma unroll
            for (int i = 0; i < FUTN - 1; ++i) rsh[i] = fma(sv, fut[i], rsh[i + 1]);
            rsh[FUTN - 1] = sv * fut[FUTN - 1];
            sr[t] = (unsigned char)(sv != 0.0 ? 1 : 0);
        }
    }
    __syncthreads();

    // spikes -> global (uchar, coalesced via uint)
    {
        const int tl2 = tid & 63;
#pragma unroll
        for (int r = 0; r < 4; ++r) {
            const int c = (tid >> 6) + 4 * r;
            const unsigned int v = *(const unsigned int*)&sb[c * 260 + 4 * tl2];
            *(unsigned int*)&s1[((size_t)b * HIDD + cbase + c0l + c) * TT + 4 * tl2] = v;
        }
    }
}

// ---------------- layer 2a: m2 = W2 . s1 (f64), parallel over b x t ---------
__global__ __launch_bounds__(256, 2)
void layer2a_kernel(const unsigned char* __restrict__ s1,
                    const double* __restrict__ w2d, double* __restrict__ m2)
{
    __shared__ double w2l[OUTC * HIDD];    // 40 KB
    __shared__ double red[4][OUTC][65];    // 20.8 KB

    const int tid = threadIdx.x;
    const int b = blockIdx.x, q = blockIdx.y;
    const int tl = tid & 63, hq = tid >> 6;
    const int t  = q * 64 + tl;

    for (int u = tid; u < OUTC * HIDD; u += 256) w2l[u] = w2d[u];
    __syncthreads();

    double p[OUTC];
#pragma unroll
    for (int oc = 0; oc < OUTC; ++oc) p[oc] = 0.0;

    const unsigned char* sp = s1 + ((size_t)b * HIDD + hq * 128) * TT + t;
    for (int h0 = 0; h0 < 128; ++h0) {
        const double sv = (double)sp[(size_t)h0 * TT];
        const int h = hq * 128 + h0;
#pragma unroll
        for (int oc = 0; oc < OUTC; ++oc)
            p[oc] = fma(sv, w2l[oc * HIDD + h], p[oc]);
    }
#pragma unroll
    for (int oc = 0; oc < OUTC; ++oc) red[hq][oc][tl] = p[oc];
    __syncthreads();

    for (int u = tid; u < OUTC * 64; u += 256) {
        const int oc = u >> 6, t2 = u & 63;
        const double s = ((red[0][oc][t2] + red[1][oc][t2]) +
                          red[2][oc][t2]) + red[3][oc][t2];
        m2[((size_t)b * OUTC + oc) * TT + q * 64 + t2] = s;
    }
}

// ---------------- layer 2b: FIR + spike scan on m2 --------------------------
__global__ __launch_bounds__(256)
void layer2b_kernel(const double* __restrict__ m2, const float* __restrict__ srm,
                    const float* __restrict__ refk, float* __restrict__ out,
                    int Ks, int Kr)
{
    __shared__ double mh[OUTC][257];
    __shared__ double uh[OUTC][257];
    __shared__ double srm_sm[KSMAX];
    __shared__ unsigned char s2[OUTC][260];

    const int tid = threadIdx.x;       // == t
    const int b   = blockIdx.x;

    if (tid < KSMAX) srm_sm[tid] = (tid < Ks) ? (double)srm[tid] : 0.0;
    for (int u = tid; u < OUTC * TT; u += 256)
        mh[u >> 8][u & 255] = m2[(size_t)b * OUTC * TT + u];
    __syncthreads();

    double p[OUTC];
#pragma unroll
    for (int oc = 0; oc < OUTC; ++oc) p[oc] = 0.0;
    for (int j = 0; j < KSMAX; ++j) {
        const int idx = tid - j;
        if (idx >= 0) {
            const double sj = srm_sm[j];
#pragma unroll
            for (int oc = 0; oc < OUTC; ++oc)
                p[oc] = fma(mh[oc][idx], sj, p[oc]);
        }
    }
#pragma unroll
    for (int oc = 0; oc < OUTC; ++oc) uh[oc][tid] = p[oc];
    __syncthreads();

    if (tid < OUTC) {
        double fut[FUTN], rsh[FUTN];
#pragma unroll
        for (int i = 0; i < FUTN; ++i) {
            fut[i] = (i + 1 < Kr) ? (double)refk[i + 1] : 0.0;
            rsh[i] = 0.0;
        }
        for (int t = 0; t < TT; ++t) {
            const double m  = uh[tid][t] + rsh[0];
            const double sv = (m >= THETA) ? 1.0 : 0.0;
#pragma unroll
            for (int i = 0; i < FUTN - 1; ++i) rsh[i] = fma(sv, fut[i], rsh[i + 1]);
            rsh[FUTN - 1] = sv * fut[FUTN - 1];
            s2[tid][t] = (unsigned char)(sv != 0.0 ? 1 : 0);
        }
    }
    __syncthreads();

    for (int u = tid; u < OUTC * TT; u += 256)
        out[(size_t)b * OUTC * TT + u] = (float)s2[u >> 8][u & 255];
}

extern "C" void kernel_launch(void* const* d_in, const int* in_sizes, int n_in,
                              void* d_out, int out_size, void* d_ws, size_t ws_size,
                              hipStream_t stream)
{
    const int*   feed = (const int*)  d_in[0];
    const float* emb  = (const float*)d_in[1];
    const float* W1   = (const float*)d_in[2];
    const float* W2   = (const float*)d_in[3];
    const float* srm  = (const float*)d_in[4];
    const float* refk = (const float*)d_in[5];
    const int Ks = in_sizes[4];
    const int Kr = in_sizes[5];

    // ws layout: [s1 8,388,608][w2d 40,960][m2 1,310,720][m1 chunk ...]
    const size_t S1B  = (size_t)BB * HIDD * TT;          // 8,388,608
    const size_t W2DB = (size_t)OUTC * HIDD * 8;         // 40,960
    const size_t M2B  = (size_t)BB * OUTC * TT * 8;      // 1,310,720
    unsigned char* s1c = (unsigned char*)d_ws;
    double* w2d = (double*)((char*)d_ws + S1B);
    double* m2  = (double*)((char*)d_ws + S1B + W2DB);
    double* m1  = (double*)((char*)d_ws + S1B + W2DB + M2B);
    const size_t fixed = S1B + W2DB + M2B;
    const size_t avail = (ws_size > fixed) ? ws_size - fixed : 0;

    // largest channel chunk whose m1 (B*chn*T f64) fits in remaining ws
    int chn = 32;
    if ((size_t)BB * 512 * TT * 8 <= avail) chn = 512;
    else if ((size_t)BB * 256 * TT * 8 <= avail) chn = 256;
    else if ((size_t)BB * 128 * TT * 8 <= avail) chn = 128;
    else if ((size_t)BB *  64 * TT * 8 <= avail) chn = 64;

    float* out = (float*)d_out;

    w2cvt_kernel<<<dim3(20), 256, 0, stream>>>(W2, w2d);
    for (int cb = 0; cb < HIDD; cb += chn) {
        gemm1_kernel  <<<dim3(chn / CTILE, BB), 256, 0, stream>>>(
            feed, emb, W1, m1, cb, chn);
        firscan_kernel<<<dim3(chn / 16, BB),    256, 0, stream>>>(
            m1, srm, refk, s1c, Ks, Kr, cb, chn);
    }
    layer2a_kernel<<<dim3(BB, 4), 256, 0, stream>>>(s1c, w2d, m2);
    layer2b_kernel<<<dim3(BB),    256, 0, stream>>>(m2, srm, refk, out, Ks, Kr);
}

// Round 7
// 439.649 us; speedup vs baseline: 1.6817x; 1.6817x over previous
//
#include <hip/hip_runtime.h>

#define BB    64
#define TT    256
#define EMBD  300
#define HIDD  512
#define OUTC  10
#define THETA 10.0
#define FUTN  12     // >= Kr-1 (Kr expected 11)
#define KSMAX 80     // >= Ks (expected 77), srm zero-padded
#define XSTR  260    // LDS x row stride (floats)
#define WSTR  34     // LDS w row stride (doubles), even -> 16B-aligned b128 rows
#define HSTR  257    // LDS h row stride (doubles)
#define CTILE 32

// ---------------- tiny: W2 f32 -> f64 ---------------------------------------
__global__ __launch_bounds__(256)
void w2cvt_kernel(const float* __restrict__ W2, double* __restrict__ w2d)
{
    const int k = blockIdx.x * 256 + threadIdx.x;
    if (k < OUTC * HIDD) w2d[k] = (double)W2[k];
}

// ------- gemm1: m1[b][c-cbase][t] = sum_e W1[c][e] * emb[feed[b][t]][e] -----
__global__ __launch_bounds__(256, 3)
void gemm1_kernel(const int* __restrict__ feed, const float* __restrict__ emb,
                  const float* __restrict__ W1, double* __restrict__ m1,
                  int cbase, int chn)
{
    __shared__ float  xs[16 * XSTR];   // [e][t] f32, 16.6 KB
    __shared__ double wl[16 * WSTR];   // [e][c] f64, 4.4 KB
    __shared__ int    idxb[TT];

    const int tid = threadIdx.x;
    const int c0l = blockIdx.x * CTILE;      // local channel base in chunk
    const int c0  = cbase + c0l;             // global channel base
    const int b   = blockIdx.y;

    idxb[tid] = feed[b * TT + tid];
    __syncthreads();

    const int cg = tid >> 6, tg = tid & 63;   // compute: c=8cg+j, t=4tg+i
    const int es = tid & 15, ts = tid >> 4;   // staging: e lane, t base

    int myidx[16];
#pragma unroll
    for (int k = 0; k < 16; ++k) myidx[k] = idxb[ts + 16 * k];

    double acc[4][8];
#pragma unroll
    for (int i = 0; i < 4; ++i)
#pragma unroll
        for (int j = 0; j < 8; ++j) acc[i][j] = 0.0;

    const int NCH = (EMBD + 15) / 16;  // 19
    for (int ch = 0; ch < NCH; ++ch) {
        const int e0 = ch * 16;
        const int ec = min(16, EMBD - e0);
        // stage x: xs[e][t] = emb[idx[t]][e0+e]
        if (es < ec) {
#pragma unroll
            for (int k = 0; k < 16; ++k) {
                const int t = ts + 16 * k;
                xs[es * XSTR + t] = emb[(size_t)myidx[k] * EMBD + e0 + es];
            }
        }
        // stage w: 32c x 16e, f64
        {
            int u = tid;
#pragma unroll
            for (int rep = 0; rep < 2; ++rep) {
                const int c = u >> 4, e = u & 15;
                if (e < ec)
                    wl[e * WSTR + c] = (double)W1[(size_t)(c0 + c) * EMBD + e0 + e];
                u += 256;
            }
        }
        __syncthreads();
        for (int e = 0; e < ec; ++e) {
            const float4  xv = *(const float4*)&xs[e * XSTR + 4 * tg];
            const double* wp = &wl[e * WSTR + 8 * cg];
            const double2 w01 = *(const double2*)(wp + 0);
            const double2 w23 = *(const double2*)(wp + 2);
            const double2 w45 = *(const double2*)(wp + 4);
            const double2 w67 = *(const double2*)(wp + 6);
            const double wv[8] = { w01.x, w01.y, w23.x, w23.y,
                                   w45.x, w45.y, w67.x, w67.y };
            const double xd[4] = { (double)xv.x, (double)xv.y,
                                   (double)xv.z, (double)xv.w };
#pragma unroll
            for (int i = 0; i < 4; ++i)
#pragma unroll
                for (int j = 0; j < 8; ++j)
                    acc[i][j] = fma(xd[i], wv[j], acc[i][j]);
        }
        __syncthreads();
    }

    // write m1 (coalesced: 64 lanes x 32B per c-row)
#pragma unroll
    for (int j = 0; j < 8; ++j) {
        double* dst = &m1[((size_t)b * chn + c0l + 8 * cg + j) * TT + 4 * tg];
        *(double2*)(dst + 0) = make_double2(acc[0][j], acc[1][j]);
        *(double2*)(dst + 2) = make_double2(acc[2][j], acc[3][j]);
    }
}

// ---------------- firscan: psp FIR + spike scan per (b, 16c) ----------------
__global__ __launch_bounds__(256)
void firscan_kernel(const double* __restrict__ m1, const float* __restrict__ srm,
                    const float* __restrict__ refk, unsigned char* __restrict__ s1,
                    int Ks, int Kr, int cbase, int chn)
{
    __shared__ double        h[16 * HSTR];     // 32.9 KB
    __shared__ unsigned char sb[16 * 260];     // 4.2 KB
    __shared__ double        srm_sm[KSMAX];

    const int tid = threadIdx.x;
    const int c0l = blockIdx.x * 16;
    const int b   = blockIdx.y;

    if (tid < KSMAX) srm_sm[tid] = (tid < Ks) ? (double)srm[tid] : 0.0;

    for (int u = tid; u < 16 * TT; u += 256)
        h[(u >> 8) * HSTR + (u & 255)] =
            m1[((size_t)b * chn + c0l + (u >> 8)) * TT + (u & 255)];
    __syncthreads();

    // FIR: two passes of 8 outputs; j ascending 0..KSMAX-1 -> bit-identical
    const int cf = tid & 15, tb = tid >> 4;
    const double* hrow = &h[cf * HSTR];
    double pout[16];
#pragma unroll
    for (int k = 0; k < 16; ++k) pout[k] = 0.0;
#pragma unroll
    for (int pp = 0; pp < 2; ++pp) {
        const int t0 = tb * 16 + pp * 8;
        double win[8];
#pragma unroll
        for (int k = 0; k < 8; ++k) win[k] = hrow[t0 + k];
        for (int jb = 0; jb < KSMAX; jb += 8) {
#pragma unroll
            for (int jj = 0; jj < 8; ++jj) {
                const double sj = srm_sm[jb + jj];
#pragma unroll
                for (int i = 0; i < 8; ++i)
                    pout[pp * 8 + i] = fma(win[(8 + i - jj) & 7], sj, pout[pp * 8 + i]);
                const int idx = t0 - (jb + jj) - 1;
                win[(7 - jj) & 7] = (idx >= 0) ? hrow[idx] : 0.0;
            }
        }
    }
    __syncthreads();                   // all FIR reads done before overwrite
#pragma unroll
    for (int k = 0; k < 16; ++k)
        h[cf * HSTR + tb * 16 + k] = pout[k];
    __syncthreads();

    // spike scan: 16 lanes, one per channel
    if (tid < 16) {
        double fut[FUTN], rsh[FUTN];
#pragma unroll
        for (int i = 0; i < FUTN; ++i) {
            fut[i] = (i + 1 < Kr) ? (double)refk[i + 1] : 0.0;
            rsh[i] = 0.0;
        }
        const double*  hr = &h[tid * HSTR];
        unsigned char* sr = &sb[tid * 260];
        for (int t = 0; t < TT; ++t) {
            const double m  = hr[t] + rsh[0];
            const double sv = (m >= THETA) ? 1.0 : 0.0;
#pragma unroll
            for (int i = 0; i < FUTN - 1; ++i) rsh[i] = fma(sv, fut[i], rsh[i + 1]);
            rsh[FUTN - 1] = sv * fut[FUTN - 1];
            sr[t] = (unsigned char)(sv != 0.0 ? 1 : 0);
        }
    }
    __syncthreads();

    // spikes -> global (uchar, coalesced via uint)
    {
        const int tl2 = tid & 63;
#pragma unroll
        for (int r = 0; r < 4; ++r) {
            const int c = (tid >> 6) + 4 * r;
            const unsigned int v = *(const unsigned int*)&sb[c * 260 + 4 * tl2];
            *(unsigned int*)&s1[((size_t)b * HIDD + cbase + c0l + c) * TT + 4 * tl2] = v;
        }
    }
}

// ---------------- layer 2a: m2 = W2 . s1 (f64), parallel over b x t ---------
__global__ __launch_bounds__(256, 2)
void layer2a_kernel(const unsigned char* __restrict__ s1,
                    const double* __restrict__ w2d, double* __restrict__ m2)
{
    __shared__ double w2l[OUTC * HIDD];    // 40 KB
    __shared__ double red[4][OUTC][65];    // 20.8 KB

    const int tid = threadIdx.x;
    const int b = blockIdx.x, q = blockIdx.y;
    const int tl = tid & 63, hq = tid >> 6;
    const int t  = q * 64 + tl;

    for (int u = tid; u < OUTC * HIDD; u += 256) w2l[u] = w2d[u];
    __syncthreads();

    double p[OUTC];
#pragma unroll
    for (int oc = 0; oc < OUTC; ++oc) p[oc] = 0.0;

    const unsigned char* sp = s1 + ((size_t)b * HIDD + hq * 128) * TT + t;
    for (int h0 = 0; h0 < 128; ++h0) {
        const double sv = (double)sp[(size_t)h0 * TT];
        const int h = hq * 128 + h0;
#pragma unroll
        for (int oc = 0; oc < OUTC; ++oc)
            p[oc] = fma(sv, w2l[oc * HIDD + h], p[oc]);
    }
#pragma unroll
    for (int oc = 0; oc < OUTC; ++oc) red[hq][oc][tl] = p[oc];
    __syncthreads();

    for (int u = tid; u < OUTC * 64; u += 256) {
        const int oc = u >> 6, t2 = u & 63;
        const double s = ((red[0][oc][t2] + red[1][oc][t2]) +
                          red[2][oc][t2]) + red[3][oc][t2];
        m2[((size_t)b * OUTC + oc) * TT + q * 64 + t2] = s;
    }
}

// ---------------- layer 2b: FIR + spike scan on m2 --------------------------
__global__ __launch_bounds__(256)
void layer2b_kernel(const double* __restrict__ m2, const float* __restrict__ srm,
                    const float* __restrict__ refk, float* __restrict__ out,
                    int Ks, int Kr)
{
    __shared__ double mh[OUTC][257];
    __shared__ double uh[OUTC][257];
    __shared__ double srm_sm[KSMAX];
    __shared__ unsigned char s2[OUTC][260];

    const int tid = threadIdx.x;       // == t
    const int b   = blockIdx.x;

    if (tid < KSMAX) srm_sm[tid] = (tid < Ks) ? (double)srm[tid] : 0.0;
    for (int u = tid; u < OUTC * TT; u += 256)
        mh[u >> 8][u & 255] = m2[(size_t)b * OUTC * TT + u];
    __syncthreads();

    double p[OUTC];
#pragma unroll
    for (int oc = 0; oc < OUTC; ++oc) p[oc] = 0.0;
    for (int j = 0; j < KSMAX; ++j) {
        const int idx = tid - j;
        if (idx >= 0) {
            const double sj = srm_sm[j];
#pragma unroll
            for (int oc = 0; oc < OUTC; ++oc)
                p[oc] = fma(mh[oc][idx], sj, p[oc]);
        }
    }
#pragma unroll
    for (int oc = 0; oc < OUTC; ++oc) uh[oc][tid] = p[oc];
    __syncthreads();

    if (tid < OUTC) {
        double fut[FUTN], rsh[FUTN];
#pragma unroll
        for (int i = 0; i < FUTN; ++i) {
            fut[i] = (i + 1 < Kr) ? (double)refk[i + 1] : 0.0;
            rsh[i] = 0.0;
        }
        for (int t = 0; t < TT; ++t) {
            const double m  = uh[tid][t] + rsh[0];
            const double sv = (m >= THETA) ? 1.0 : 0.0;
#pragma unroll
            for (int i = 0; i < FUTN - 1; ++i) rsh[i] = fma(sv, fut[i], rsh[i + 1]);
            rsh[FUTN - 1] = sv * fut[FUTN - 1];
            s2[tid][t] = (unsigned char)(sv != 0.0 ? 1 : 0);
        }
    }
    __syncthreads();

    for (int u = tid; u < OUTC * TT; u += 256)
        out[(size_t)b * OUTC * TT + u] = (float)s2[u >> 8][u & 255];
}

extern "C" void kernel_launch(void* const* d_in, const int* in_sizes, int n_in,
                              void* d_out, int out_size, void* d_ws, size_t ws_size,
                              hipStream_t stream)
{
    const int*   feed = (const int*)  d_in[0];
    const float* emb  = (const float*)d_in[1];
    const float* W1   = (const float*)d_in[2];
    const float* W2   = (const float*)d_in[3];
    const float* srm  = (const float*)d_in[4];
    const float* refk = (const float*)d_in[5];
    const int Ks = in_sizes[4];
    const int Kr = in_sizes[5];

    // ws layout: [s1 8,388,608][w2d 40,960][m2 1,310,720][m1 chunk ...]
    const size_t S1B  = (size_t)BB * HIDD * TT;          // 8,388,608
    const size_t W2DB = (size_t)OUTC * HIDD * 8;         // 40,960
    const size_t M2B  = (size_t)BB * OUTC * TT * 8;      // 1,310,720
    unsigned char* s1c = (unsigned char*)d_ws;
    double* w2d = (double*)((char*)d_ws + S1B);
    double* m2  = (double*)((char*)d_ws + S1B + W2DB);
    double* m1  = (double*)((char*)d_ws + S1B + W2DB + M2B);
    const size_t fixed = S1B + W2DB + M2B;
    const size_t avail = (ws_size > fixed) ? ws_size - fixed : 0;

    // largest channel chunk whose m1 (B*chn*T f64) fits in remaining ws
    int chn = 32;
    if ((size_t)BB * 512 * TT * 8 <= avail) chn = 512;
    else if ((size_t)BB * 256 * TT * 8 <= avail) chn = 256;
    else if ((size_t)BB * 128 * TT * 8 <= avail) chn = 128;
    else if ((size_t)BB *  64 * TT * 8 <= avail) chn = 64;

    float* out = (float*)d_out;

    w2cvt_kernel<<<dim3(20), 256, 0, stream>>>(W2, w2d);
    for (int cb = 0; cb < HIDD; cb += chn) {
        gemm1_kernel  <<<dim3(chn / CTILE, BB), 256, 0, stream>>>(
            feed, emb, W1, m1, cb, chn);
        firscan_kernel<<<dim3(chn / 16, BB),    256, 0, stream>>>(
            m1, srm, refk, s1c, Ks, Kr, cb, chn);
    }
    layer2a_kernel<<<dim3(BB, 4), 256, 0, stream>>>(s1c, w2d, m2);
    layer2b_kernel<<<dim3(BB),    256, 0, stream>>>(m2, srm, refk, out, Ks, Kr);
}